// Round 8
// baseline (459.766 us; speedup 1.0000x reference)
//
#include <hip/hip_runtime.h>
#include <math.h>

// Problem constants
#define NPX   1048576      // 1024*1024
#define TD    1025         // tex_eval spatial dim
#define PW    35           // patch width (cells) for 32-wide tile
#define PH    11           // patch height (cells) for 8-tall tile
// ws layout: [0, 16KB)            ffrag_g fp16 [kk][lane][8] (MFMA frag order)
//            [48KB, +33.62MB)     tex     fp16 [y][x][c]  (TD*TD*16)

typedef _Float16 half8 __attribute__((ext_vector_type(8)));
typedef _Float16 half4 __attribute__((ext_vector_type(4)));
typedef float    f32x4 __attribute__((ext_vector_type(4)));

// ------- Stage 1: MLP -> MFMA fragment-ordered fp16 filter (fused) -----------
__global__ __launch_bounds__(256) void mlp_kernel(
    const float* __restrict__ expr,
    const float* __restrict__ W1, const float* __restrict__ b1,
    const float* __restrict__ W2, const float* __restrict__ b2,
    const float* __restrict__ W3, const float* __restrict__ b3,
    _Float16* __restrict__ ffrag_g)
{
    __shared__ float sx[76];
    __shared__ float sh1[128];
    __shared__ float sh2[64];
    int t = threadIdx.x;
    if (t < 76) sx[t] = expr[t];
    __syncthreads();
    if (t < 128) {
        float a = b1[t];
        const float* w = W1 + t * 76;
        #pragma unroll 4
        for (int i = 0; i < 76; ++i) a += sx[i] * w[i];
        sh1[t] = a >= 0.f ? a : 0.02f * a;
    }
    __syncthreads();
    if (t < 64) {
        float a = b2[t];
        const float* w = W2 + t * 128;
        #pragma unroll 4
        for (int i = 0; i < 128; ++i) a += sh1[i] * w[i];
        sh2[t] = a >= 0.f ? a : 0.02f * a;
    }
    __syncthreads();
    int o = blockIdx.x * 256 + t;            // 0..8191
    float a = b3[o];
    const float* w = W3 + o * 64;
    #pragma unroll 4
    for (int i = 0; i < 64; ++i) a += sh2[i] * w[i];
    a = tanhf(a);
    int oc = o >> 9;                          // o / 512
    int ic = (o >> 4) & 31;
    int kk = o & 15;                          // ky*4+kx
    ffrag_g[(size_t)(kk * 64 + (ic >> 3) * 16 + oc) * 8 + (ic & 7)] = (_Float16)a;
}

// ------- Stage 2: FUSED repack + implicit-GEMM conv via 16x16x32 MFMA --------
// R8 (R7 post-mortem: VGPR_Count=60 proved the scheduler re-interleaved the
// load/store passes to cut register pressure, reintroducing per-chunk vmcnt
// round-trips -> 2.55 TB/s). Two paired fixes:
//  (1) sched_barrier(0) between load pass and store pass — a single phase
//      boundary pin so all 14 loads issue back-to-back (~14 KB in flight/wave).
//  (2) occupancy 4->6 blocks/CU: the persistent 64-VGPR bfrag[16] array is
//      gone; the MFMA loop loads each b-fragment per-kk from ffrag_g (8 KB,
//      L1-hot, compile-time kk -> imm-offset dwordx4). Staging peak ~75 VGPR
//      now fits the (256,6) ~85-VGPR budget without scratch demotion.
__global__ __launch_bounds__(256, 6) void conv_mfma_kernel(
    const float* __restrict__ data,          // [32][1024][1024] fp32 NCHW
    const _Float16* __restrict__ ffrag_g,    // [16][64][8] fp16
    _Float16* __restrict__ tex)              // [1025][1025][16] fp16
{
    __shared__ __attribute__((aligned(128))) _Float16 sp[PH * PW * 32]; // 24,640 B

    int tid = threadIdx.x;
    int l = tid & 63, w = tid >> 6;
    int ox0 = blockIdx.x * 32;
    int oy0 = blockIdx.y * 8;

    // ---- staging pass 1: issue ALL global loads (14 outstanding/thread) ----
    // Chunk space: g = r*320 + c*10 + xg  (r<11 rows, c<32 ch, xg<10 f32x4).
    // Cell (r,xL,c) <-> global (oy0+r-2, ox0-2+xL, c); gx = ox0-4+xg*4.
    f32x4 v[14];
    #pragma unroll
    for (int it = 0; it < 14; ++it) {
        v[it] = (f32x4){0.f, 0.f, 0.f, 0.f};
        int g = tid + it * 256;
        int r = g / 320;
        int rem = g - r * 320;
        int c = rem / 10;
        int xg = rem - c * 10;
        int gy = oy0 + r - 2;
        int gx = (ox0 - 4) + xg * 4;         // 16-B aligned
        if (g < 3520 && (unsigned)gy < 1024u) {
            const float* src = data + (size_t)c * NPX + ((size_t)gy << 10) + gx;
            if ((unsigned)gx <= 1020u) {
                v[it] = *(const f32x4*)src;
            } else {
                #pragma unroll
                for (int k = 0; k < 4; ++k)
                    if ((unsigned)(gx + k) < 1024u) v[it][k] = src[k];
            }
        }
    }

    // Phase boundary: forbid sinking the LDS stores into the load burst.
    __builtin_amdgcn_sched_barrier(0);

    // ---- staging pass 2: convert + swizzled LDS writes (pipelined drain) ----
    // LDS byte for (r, xL, c): chunk = xL*4 + (c>>3); swc = chunk^((chunk>>3)&7);
    // byte = r*2240 + swc*16 + (c&7)*2.  (~2-way bank aliasing: free.)
    #pragma unroll
    for (int it = 0; it < 14; ++it) {
        int g = tid + it * 256;
        if (g >= 3520) continue;
        int r = g / 320;
        int rem = g - r * 320;
        int c = rem / 10;
        int xg = rem - c * 10;
        char* lrow = (char*)sp + r * 2240;
        int q8 = c >> 3, c7 = (c & 7) * 2;
        #pragma unroll
        for (int k = 0; k < 4; ++k) {
            int xL = xg * 4 + k - 2;
            if ((unsigned)xL < 35u) {
                int chunk = xL * 4 + q8;
                int swc = chunk ^ ((chunk >> 3) & 7);
                *(_Float16*)(lrow + swc * 16 + c7) = (_Float16)v[it][k];
            }
        }
    }

    __syncthreads();

    int lane15 = l & 15;
    int q = l >> 4;

    // Swizzled A-frag byte offsets: logical chunk in row = (t&1)*64 + kx*4 + u;
    // the (t&1)*64 term commutes with the XOR (bit 6 untouched).
    int u = lane15 * 4 + q;
    int sv[4];
    #pragma unroll
    for (int kx = 0; kx < 4; ++kx) {
        int vch = kx * 4 + u;
        sv[kx] = (vch ^ ((vch >> 3) & 7)) * 16;    // byte offset in row
    }

    f32x4 acc[4];
    #pragma unroll
    for (int t = 0; t < 4; ++t) acc[t] = (f32x4){0.f, 0.f, 0.f, 0.f};

    // m-tile t: tile row (w*2 + (t>>1)), x half (t&1); lane pixel = lane15.
    // b-fragment loaded per-kk (compile-time kk -> imm offset; L1-hot 8 KB).
    #pragma unroll
    for (int kk = 0; kk < 16; ++kk) {
        int ky = kk >> 2, kx = kk & 3;
        half8 bf = *(const half8*)&ffrag_g[kk * 512 + l * 8];
        #pragma unroll
        for (int t = 0; t < 4; ++t) {
            const char* ap = (const char*)sp
                + (w * 2 + (t >> 1) + ky) * (PW * 64)  // row * 2240 B
                + (t & 1) * 1024 + sv[kx];
            half8 af = *(const half8*)ap;
            // swapped operands: D col = lane&15 = pixel, row = q*4+reg = channel
            acc[t] = __builtin_amdgcn_mfma_f32_16x16x32_f16(bf, af, acc[t], 0, 0, 0);
        }
    }

    // epilogue: lane holds channels q*4..q*4+3 of pixel px. One 8-B packed
    // store per tile; wave covers 512 contiguous bytes per instruction.
    #pragma unroll
    for (int t = 0; t < 4; ++t) {
        int oy = oy0 + w * 2 + (t >> 1);
        int px = ox0 + (t & 1) * 16 + lane15;
        if (oy > 1024 || px > 1024) continue;
        half4 hv;
        #pragma unroll
        for (int r = 0; r < 4; ++r) hv[r] = (_Float16)acc[t][r];
        *(half4*)&tex[((size_t)oy * TD + px) * 16 + q * 4] = hv;
    }
}

// ---------------- Stage 3: bilinear grid-sample (border pad) -----------------
// 1 px/thread, max occupancy (accounting across R1-R3: the 2-px/thread ILP
// variant cost ~+10-17 us vs this form).
__global__ __launch_bounds__(256, 6) void sample_kernel(
    const float* __restrict__ uv,            // [2][1024][1024]
    const _Float16* __restrict__ tex,        // [1025][1025][16] fp16
    float* __restrict__ out)                 // [16][1024][1024]
{
    int p = blockIdx.x * 256 + threadIdx.x;  // 0..NPX-1
    float x = __builtin_nontemporal_load(&uv[p]);
    float y = __builtin_nontemporal_load(&uv[NPX + p]);
    float ix = fminf(fmaxf(((x + 1.f) * 1025.f - 1.f) * 0.5f, 0.f), 1024.f);
    float iy = fminf(fmaxf(((y + 1.f) * 1025.f - 1.f) * 0.5f, 0.f), 1024.f);
    float fx0 = floorf(ix), fy0 = floorf(iy);
    float wx = ix - fx0, wy = iy - fy0;
    int x0 = (int)fx0, y0 = (int)fy0;
    int x1 = min(x0 + 1, 1024), y1 = min(y0 + 1, 1024);

    const half8* t00 = (const half8*)(tex + ((size_t)y0 * TD + x0) * 16);
    const half8* t01 = (const half8*)(tex + ((size_t)y0 * TD + x1) * 16);
    const half8* t10 = (const half8*)(tex + ((size_t)y1 * TD + x0) * 16);
    const half8* t11 = (const half8*)(tex + ((size_t)y1 * TD + x1) * 16);

    half8 v0 = t00[0], v1 = t00[1];
    half8 v2 = t01[0], v3 = t01[1];
    half8 v4 = t10[0], v5 = t10[1];
    half8 v6 = t11[0], v7 = t11[1];

    float w00 = (1.f - wx) * (1.f - wy);
    float w01 = wx * (1.f - wy);
    float w10 = (1.f - wx) * wy;
    float w11 = wx * wy;

    #pragma unroll
    for (int c = 0; c < 8; ++c) {
        float r0 = (float)v0[c] * w00 + (float)v2[c] * w01
                 + (float)v4[c] * w10 + (float)v6[c] * w11;
        float r1 = (float)v1[c] * w00 + (float)v3[c] * w01
                 + (float)v5[c] * w10 + (float)v7[c] * w11;
        __builtin_nontemporal_store(r0, &out[(size_t)c * NPX + p]);
        __builtin_nontemporal_store(r1, &out[(size_t)(c + 8) * NPX + p]);
    }
}

extern "C" void kernel_launch(void* const* d_in, const int* in_sizes, int n_in,
                              void* d_out, int out_size, void* d_ws, size_t ws_size,
                              hipStream_t stream) {
    const float* expr = (const float*)d_in[0];
    // d_in[1] = audio_features: unused by the reference
    const float* uv   = (const float*)d_in[2];
    const float* data = (const float*)d_in[3];
    const float* W1   = (const float*)d_in[4];
    const float* b1   = (const float*)d_in[5];
    const float* W2   = (const float*)d_in[6];
    const float* b2   = (const float*)d_in[7];
    const float* W3   = (const float*)d_in[8];
    const float* b3   = (const float*)d_in[9];
    float* out = (float*)d_out;

    _Float16* ffrag_g  = (_Float16*)d_ws;                            // 16 KB
    _Float16* tex      = (_Float16*)((char*)d_ws + 49152);           // 33.62 MB

    mlp_kernel<<<32, 256, 0, stream>>>(expr, W1, b1, W2, b2, W3, b3, ffrag_g);
    conv_mfma_kernel<<<dim3(33, 129), 256, 0, stream>>>(data, ffrag_g, tex);
    sample_kernel<<<NPX / 256, 256, 0, stream>>>(uv, tex, out);
}

// Round 9
// 343.074 us; speedup vs baseline: 1.3401x; 1.3401x over previous
//
#include <hip/hip_runtime.h>
#include <math.h>

// Problem constants
#define NPX   1048576      // 1024*1024
#define TD    1025         // tex_eval spatial dim
#define PW    35           // patch width (cells) for 32-wide tile
#define PH    11           // patch height (cells) for 8-tall tile
// ws layout: [0, 16KB)            ffrag_g fp16 [kk][lane][8] (MFMA frag order)
//            [48KB, +33.62MB)     tex     fp16 [y][x][c]  (TD*TD*16)

typedef _Float16 half8 __attribute__((ext_vector_type(8)));
typedef _Float16 half4 __attribute__((ext_vector_type(4)));
typedef float    f32x4 __attribute__((ext_vector_type(4)));

// ------- Stage 1: MLP -> MFMA fragment-ordered fp16 filter (fused) -----------
__global__ __launch_bounds__(256) void mlp_kernel(
    const float* __restrict__ expr,
    const float* __restrict__ W1, const float* __restrict__ b1,
    const float* __restrict__ W2, const float* __restrict__ b2,
    const float* __restrict__ W3, const float* __restrict__ b3,
    _Float16* __restrict__ ffrag_g)
{
    __shared__ float sx[76];
    __shared__ float sh1[128];
    __shared__ float sh2[64];
    int t = threadIdx.x;
    if (t < 76) sx[t] = expr[t];
    __syncthreads();
    if (t < 128) {
        float a = b1[t];
        const float* w = W1 + t * 76;
        #pragma unroll 4
        for (int i = 0; i < 76; ++i) a += sx[i] * w[i];
        sh1[t] = a >= 0.f ? a : 0.02f * a;
    }
    __syncthreads();
    if (t < 64) {
        float a = b2[t];
        const float* w = W2 + t * 128;
        #pragma unroll 4
        for (int i = 0; i < 128; ++i) a += sh1[i] * w[i];
        sh2[t] = a >= 0.f ? a : 0.02f * a;
    }
    __syncthreads();
    int o = blockIdx.x * 256 + t;            // 0..8191
    float a = b3[o];
    const float* w = W3 + o * 64;
    #pragma unroll 4
    for (int i = 0; i < 64; ++i) a += sh2[i] * w[i];
    a = tanhf(a);
    int oc = o >> 9;                          // o / 512
    int ic = (o >> 4) & 31;
    int kk = o & 15;                          // ky*4+kx
    ffrag_g[(size_t)(kk * 64 + (ic >> 3) * 16 + oc) * 8 + (ic & 7)] = (_Float16)a;
}

// ------- Stage 2: FUSED repack + implicit-GEMM conv via 16x16x32 MFMA --------
// R9: the completed single-variable experiment. Mechanism history:
//   R7  (256,4), no fence:  compiler interleaves load/store to 60 VGPR ->
//                           serialized vmcnt round-trips, 2.5 TB/s, 114 us.
//   R8  (256,6) + fence:    ordering pinned but 85-VGPR cap -> v[14] SPILLED
//                           (VGPR=40, +244 MB scratch writes), 224 us.
//   R9  (256,4) + fence:    128-VGPR budget fits the ~80-reg live set; all
//                           14 loads burst back-to-back, stores drain after.
// ASSERTION: VGPR_Count must report ~90-120. If <=64, registers were demoted
// again and the fused design gets reverted to the R5 split.
__global__ __launch_bounds__(256, 4) void conv_mfma_kernel(
    const float* __restrict__ data,          // [32][1024][1024] fp32 NCHW
    const _Float16* __restrict__ ffrag_g,    // [16][64][8] fp16
    _Float16* __restrict__ tex)              // [1025][1025][16] fp16
{
    __shared__ __attribute__((aligned(128))) _Float16 sp[PH * PW * 32]; // 24,640 B

    int tid = threadIdx.x;
    int l = tid & 63, w = tid >> 6;
    int ox0 = blockIdx.x * 32;
    int oy0 = blockIdx.y * 8;

    // ---- staging pass 1: issue ALL global loads (14 outstanding/thread) ----
    // Chunk space: g = r*320 + c*10 + xg  (r<11 rows, c<32 ch, xg<10 f32x4).
    // Cell (r,xL,c) <-> global (oy0+r-2, ox0-2+xL, c); gx = ox0-4+xg*4.
    f32x4 v[14];
    #pragma unroll
    for (int it = 0; it < 14; ++it) {
        v[it] = (f32x4){0.f, 0.f, 0.f, 0.f};
        int g = tid + it * 256;
        int r = g / 320;
        int rem = g - r * 320;
        int c = rem / 10;
        int xg = rem - c * 10;
        int gy = oy0 + r - 2;
        int gx = (ox0 - 4) + xg * 4;         // 16-B aligned
        if (g < 3520 && (unsigned)gy < 1024u) {
            const float* src = data + (size_t)c * NPX + ((size_t)gy << 10) + gx;
            if ((unsigned)gx <= 1020u) {
                v[it] = *(const f32x4*)src;
            } else {
                #pragma unroll
                for (int k = 0; k < 4; ++k)
                    if ((unsigned)(gx + k) < 1024u) v[it][k] = src[k];
            }
        }
    }

    // Phase boundary: forbid sinking the LDS stores into the load burst.
    __builtin_amdgcn_sched_barrier(0);

    // ---- staging pass 2: convert + swizzled LDS writes (pipelined drain) ----
    // LDS byte for (r, xL, c): chunk = xL*4 + (c>>3); swc = chunk^((chunk>>3)&7);
    // byte = r*2240 + swc*16 + (c&7)*2.  (~2-way bank aliasing: free.)
    #pragma unroll
    for (int it = 0; it < 14; ++it) {
        int g = tid + it * 256;
        if (g >= 3520) continue;
        int r = g / 320;
        int rem = g - r * 320;
        int c = rem / 10;
        int xg = rem - c * 10;
        char* lrow = (char*)sp + r * 2240;
        int q8 = c >> 3, c7 = (c & 7) * 2;
        #pragma unroll
        for (int k = 0; k < 4; ++k) {
            int xL = xg * 4 + k - 2;
            if ((unsigned)xL < 35u) {
                int chunk = xL * 4 + q8;
                int swc = chunk ^ ((chunk >> 3) & 7);
                *(_Float16*)(lrow + swc * 16 + c7) = (_Float16)v[it][k];
            }
        }
    }

    __syncthreads();

    int lane15 = l & 15;
    int q = l >> 4;

    // Swizzled A-frag byte offsets: logical chunk in row = (t&1)*64 + kx*4 + u;
    // the (t&1)*64 term commutes with the XOR (bit 6 untouched).
    int u = lane15 * 4 + q;
    int sv[4];
    #pragma unroll
    for (int kx = 0; kx < 4; ++kx) {
        int vch = kx * 4 + u;
        sv[kx] = (vch ^ ((vch >> 3) & 7)) * 16;    // byte offset in row
    }

    f32x4 acc[4];
    #pragma unroll
    for (int t = 0; t < 4; ++t) acc[t] = (f32x4){0.f, 0.f, 0.f, 0.f};

    // m-tile t: tile row (w*2 + (t>>1)), x half (t&1); lane pixel = lane15.
    // b-fragment loaded per-kk (compile-time kk -> imm offset; L1-hot 8 KB),
    // keeping the staging-phase register peak as the kernel's only peak.
    #pragma unroll
    for (int kk = 0; kk < 16; ++kk) {
        int ky = kk >> 2, kx = kk & 3;
        half8 bf = *(const half8*)&ffrag_g[kk * 512 + l * 8];
        #pragma unroll
        for (int t = 0; t < 4; ++t) {
            const char* ap = (const char*)sp
                + (w * 2 + (t >> 1) + ky) * (PW * 64)  // row * 2240 B
                + (t & 1) * 1024 + sv[kx];
            half8 af = *(const half8*)ap;
            // swapped operands: D col = lane&15 = pixel, row = q*4+reg = channel
            acc[t] = __builtin_amdgcn_mfma_f32_16x16x32_f16(bf, af, acc[t], 0, 0, 0);
        }
    }

    // epilogue: lane holds channels q*4..q*4+3 of pixel px. One 8-B packed
    // store per tile; wave covers 512 contiguous bytes per instruction.
    #pragma unroll
    for (int t = 0; t < 4; ++t) {
        int oy = oy0 + w * 2 + (t >> 1);
        int px = ox0 + (t & 1) * 16 + lane15;
        if (oy > 1024 || px > 1024) continue;
        half4 hv;
        #pragma unroll
        for (int r = 0; r < 4; ++r) hv[r] = (_Float16)acc[t][r];
        *(half4*)&tex[((size_t)oy * TD + px) * 16 + q * 4] = hv;
    }
}

// ---------------- Stage 3: bilinear grid-sample (border pad) -----------------
// 1 px/thread, max occupancy (accounting across R1-R3: the 2-px/thread ILP
// variant cost ~+10-17 us vs this form).
__global__ __launch_bounds__(256, 6) void sample_kernel(
    const float* __restrict__ uv,            // [2][1024][1024]
    const _Float16* __restrict__ tex,        // [1025][1025][16] fp16
    float* __restrict__ out)                 // [16][1024][1024]
{
    int p = blockIdx.x * 256 + threadIdx.x;  // 0..NPX-1
    float x = __builtin_nontemporal_load(&uv[p]);
    float y = __builtin_nontemporal_load(&uv[NPX + p]);
    float ix = fminf(fmaxf(((x + 1.f) * 1025.f - 1.f) * 0.5f, 0.f), 1024.f);
    float iy = fminf(fmaxf(((y + 1.f) * 1025.f - 1.f) * 0.5f, 0.f), 1024.f);
    float fx0 = floorf(ix), fy0 = floorf(iy);
    float wx = ix - fx0, wy = iy - fy0;
    int x0 = (int)fx0, y0 = (int)fy0;
    int x1 = min(x0 + 1, 1024), y1 = min(y0 + 1, 1024);

    const half8* t00 = (const half8*)(tex + ((size_t)y0 * TD + x0) * 16);
    const half8* t01 = (const half8*)(tex + ((size_t)y0 * TD + x1) * 16);
    const half8* t10 = (const half8*)(tex + ((size_t)y1 * TD + x0) * 16);
    const half8* t11 = (const half8*)(tex + ((size_t)y1 * TD + x1) * 16);

    half8 v0 = t00[0], v1 = t00[1];
    half8 v2 = t01[0], v3 = t01[1];
    half8 v4 = t10[0], v5 = t10[1];
    half8 v6 = t11[0], v7 = t11[1];

    float w00 = (1.f - wx) * (1.f - wy);
    float w01 = wx * (1.f - wy);
    float w10 = (1.f - wx) * wy;
    float w11 = wx * wy;

    #pragma unroll
    for (int c = 0; c < 8; ++c) {
        float r0 = (float)v0[c] * w00 + (float)v2[c] * w01
                 + (float)v4[c] * w10 + (float)v6[c] * w11;
        float r1 = (float)v1[c] * w00 + (float)v3[c] * w01
                 + (float)v5[c] * w10 + (float)v7[c] * w11;
        __builtin_nontemporal_store(r0, &out[(size_t)c * NPX + p]);
        __builtin_nontemporal_store(r1, &out[(size_t)(c + 8) * NPX + p]);
    }
}

extern "C" void kernel_launch(void* const* d_in, const int* in_sizes, int n_in,
                              void* d_out, int out_size, void* d_ws, size_t ws_size,
                              hipStream_t stream) {
    const float* expr = (const float*)d_in[0];
    // d_in[1] = audio_features: unused by the reference
    const float* uv   = (const float*)d_in[2];
    const float* data = (const float*)d_in[3];
    const float* W1   = (const float*)d_in[4];
    const float* b1   = (const float*)d_in[5];
    const float* W2   = (const float*)d_in[6];
    const float* b2   = (const float*)d_in[7];
    const float* W3   = (const float*)d_in[8];
    const float* b3   = (const float*)d_in[9];
    float* out = (float*)d_out;

    _Float16* ffrag_g  = (_Float16*)d_ws;                            // 16 KB
    _Float16* tex      = (_Float16*)((char*)d_ws + 49152);           // 33.62 MB

    mlp_kernel<<<32, 256, 0, stream>>>(expr, W1, b1, W2, b2, W3, b3, ffrag_g);
    conv_mfma_kernel<<<dim3(33, 129), 256, 0, stream>>>(data, ffrag_g, tex);
    sample_kernel<<<NPX / 256, 256, 0, stream>>>(uv, tex, out);
}